// Round 17
// baseline (218.657 us; speedup 1.0000x reference)
//
#include <hip/hip_runtime.h>
#include <hip/hip_bf16.h>
#include <stdint.h>

typedef unsigned short u16;
typedef __attribute__((ext_vector_type(8))) short bf16x8;
typedef __attribute__((ext_vector_type(8))) unsigned short u16x8;
typedef __attribute__((ext_vector_type(4))) float f32x4;

#define BM 128
#define BN 128
#define BK 32
#define QBK 64
// folded into Q at projection: softmax scale 1/8 times log2(e)
#define QSCALE 0.18033688f

__device__ __forceinline__ u16 f2bf(float f) {
    union { float f; uint32_t u; } v; v.f = f;
    uint32_t r = v.u + 0x7FFFu + ((v.u >> 16) & 1u);
    return (u16)(r >> 16);
}

__device__ __forceinline__ uint32_t cvt_pk_bf16(float lo, float hi) {
    uint32_t r;
    asm("v_cvt_pk_bf16_f32 %0, %1, %2" : "=v"(r) : "v"(lo), "v"(hi));
    return r;
}

// raw 2^x; s_nop covers the TRANS->VALU hazard for the consumer
__device__ __forceinline__ float fexp2(float x) {
    float r;
    asm volatile("v_exp_f32 %0, %1\n\ts_nop 0" : "=v"(r) : "v"(x));
    return r;
}

__device__ __forceinline__ void gload_lds16(const void* g, void* l) {
    __builtin_amdgcn_global_load_lds(
        (const __attribute__((address_space(1))) void*)(g),
        (__attribute__((address_space(3))) void*)(l),
        16, 0, 0);
}

// ---------------- fused prep: 6 casts + rope table ----------------
__global__ void prep_kernel(const float* __restrict__ x, const float* __restrict__ ctx,
                            const float* __restrict__ Wq, const float* __restrict__ Wk,
                            const float* __restrict__ Wv, const float* __restrict__ Wo,
                            u16* __restrict__ xb, u16* __restrict__ cb,
                            u16* __restrict__ wqb, u16* __restrict__ wkb,
                            u16* __restrict__ wvb, u16* __restrict__ wob,
                            float2* __restrict__ cs) {
    int t = blockIdx.x * 256 + threadIdx.x;
    if (t < 3342336) {
        const float* src; u16* dst; int base;
        if      (t < 1048576) { src = x;   dst = xb;  base = 0; }
        else if (t < 2228224) { src = ctx; dst = cb;  base = 1048576; }
        else if (t < 2490368) { src = Wq;  dst = wqb; base = 2228224; }
        else if (t < 2785280) { src = Wk;  dst = wkb; base = 2490368; }
        else if (t < 3080192) { src = Wv;  dst = wvb; base = 2785280; }
        else                  { src = Wo;  dst = wob; base = 3080192; }
        int i = (t - base) * 4;
        float4 v = *reinterpret_cast<const float4*>(src + i);
        ushort4 o = { f2bf(v.x), f2bf(v.y), f2bf(v.z), f2bf(v.w) };
        *reinterpret_cast<ushort4*>(dst + i) = o;
    } else {
        int idx = t - 3342336;           // 0..65535
        int tt = idx >> 5, j = idx & 31;
        float invf = 1.0f / powf(10000.0f, (float)(2 * j) / 64.0f);
        float ang = (float)tt * invf;
        cs[idx] = make_float2(cosf(ang), sinf(ang));
    }
}

// ---------------- fused Q/K/V projection GEMM ----------------
// 128x128 tile, BK=64, 768 blocks = 3/CU, XCD swizzle, single-buffer 32KB LDS,
// XOR-swizzled 128B rows.
__global__ __launch_bounds__(256, 3)
void qkv_gemm(const u16* __restrict__ xb, const u16* __restrict__ cb,
              const u16* __restrict__ wqb, const u16* __restrict__ wkb,
              const u16* __restrict__ wvb,
              const float* __restrict__ bq, const float* __restrict__ bk,
              const float* __restrict__ bv,
              u16* __restrict__ qo, u16* __restrict__ ko, u16* __restrict__ vo,
              const float2* __restrict__ cs)
{
    __shared__ __align__(16) u16 As[BM * QBK];   // 16 KB
    __shared__ __align__(16) u16 Bs[BN * QBK];   // 16 KB
    const int bid = blockIdx.x;
    const int wg = (bid & 7) * 96 + (bid >> 3);
    const int seg = wg >> 8, inner = wg & 255;
    const u16* A; const u16* Bm; const float* bias; u16* C;
    int N, K, mbase, nbase, rope, brow;
    float oscale;
    if (seg == 0)      { A = xb;  Bm = wqb; bias = bq; C = qo; N = 1024; K = 1024; rope = 1; brow = 0; oscale = QSCALE; nbase = (inner & 7) * BN;  mbase = (inner >> 3) * BM; }
    else if (seg == 1) { A = cb;  Bm = wkb; bias = bk; C = ko; N = 1024; K = 1152; rope = 1; brow = 0; oscale = 1.0f;   nbase = (inner & 7) * BN;  mbase = (inner >> 3) * BM; }
    else               { A = wvb; Bm = cb;  bias = bv; C = vo; N = 4096; K = 1152; rope = 0; brow = 1; oscale = 1.0f;   nbase = (inner & 31) * BN; mbase = (inner >> 5) * BM; }

    const int tid = threadIdx.x;
    const int wid = tid >> 6, lane = tid & 63;
    const int wr = wid >> 1, wc = wid & 1;
    const int l15 = lane & 15, l4 = lane >> 4;
    const int r8 = lane >> 3;
    const int cp = lane & 7;
    const int cl = cp ^ r8;

    f32x4 acc[4][4];
#pragma unroll
    for (int i = 0; i < 4; i++)
#pragma unroll
        for (int j = 0; j < 4; j++) acc[i][j] = (f32x4){0.f, 0.f, 0.f, 0.f};

    for (int k0 = 0; k0 < K; k0 += QBK) {
#pragma unroll
        for (int q = 0; q < 4; ++q) {
            int sg = wid * 4 + q;
            int row = sg * 8 + r8;
            gload_lds16(A  + (size_t)(mbase + row) * K + k0 + cl * 8, (void*)(As + sg * 512));
            gload_lds16(Bm + (size_t)(nbase + row) * K + k0 + cl * 8, (void*)(Bs + sg * 512));
        }
        __syncthreads();
        bf16x8 af[2][4], bfv[2][4];
#pragma unroll
        for (int kk = 0; kk < 2; kk++) {
#pragma unroll
            for (int i = 0; i < 4; i++) {
                int r = wr * 64 + i * 16 + l15;
                af[kk][i] = *(const bf16x8*)(As + r * 64 + (((kk * 4 + l4) ^ (r & 7)) * 8));
            }
#pragma unroll
            for (int j = 0; j < 4; j++) {
                int r = wc * 64 + j * 16 + l15;
                bfv[kk][j] = *(const bf16x8*)(Bs + r * 64 + (((kk * 4 + l4) ^ (r & 7)) * 8));
            }
        }
        __builtin_amdgcn_s_setprio(1);
#pragma unroll
        for (int kk = 0; kk < 2; kk++)
#pragma unroll
            for (int i = 0; i < 4; i++)
#pragma unroll
                for (int j = 0; j < 4; j++)
                    acc[i][j] = __builtin_amdgcn_mfma_f32_16x16x32_bf16(af[kk][i], bfv[kk][j], acc[i][j], 0, 0, 0);
        __builtin_amdgcn_s_setprio(0);
        __syncthreads();
    }

#pragma unroll
    for (int i = 0; i < 4; i++) {
#pragma unroll
        for (int j = 0; j < 4; j++) {
#pragma unroll
            for (int r = 0; r < 4; r++) {
                int row = mbase + wr * 64 + i * 16 + l4 * 4 + r;
                int col = nbase + wc * 64 + j * 16 + l15;
                float v = acc[i][j][r] + (brow ? bias[row] : bias[col]);
                if (rope) {
                    float part = __shfl_xor(v, 1);
                    float2 c2 = cs[(row & 2047) * 32 + (col & 31)];
                    v = v * c2.x + ((col & 1) ? part * c2.y : -part * c2.y);
                    v *= oscale;
                }
                C[(size_t)row * N + col] = f2bf(v);
            }
        }
    }
}

// ---------------- O-projection GEMM: out = attn @ Wo^T + bo (f32 out) ----------------
__global__ __launch_bounds__(256, 2)
void gemm_out(const u16* __restrict__ A, const u16* __restrict__ B,
              const float* __restrict__ bias, float* __restrict__ C,
              int M, int N, int K)
{
    __shared__ __align__(16) u16 As[2][BM * BK];
    __shared__ __align__(16) u16 Bs[2][64 * BK];
    const int tid = threadIdx.x;
    const int wid = tid >> 6, lane = tid & 63;
    const int wr = wid >> 1, wc = wid & 1;
    const int l15 = lane & 15, l4 = lane >> 4;
    const int mbase = blockIdx.y * BM, nbase = blockIdx.x * 64;
    const int srow = lane >> 2;
    const int scol = (lane & 3) * 8;
    const int nk = K >> 5;

    f32x4 acc[4][2];
#pragma unroll
    for (int i = 0; i < 4; i++)
#pragma unroll
        for (int j = 0; j < 2; j++) acc[i][j] = (f32x4){0.f, 0.f, 0.f, 0.f};

    auto stage = [&](int bs, int k0) {
#pragma unroll
        for (int q = 0; q < 2; ++q) {
            int seg = wid * 2 + q;
            int row = seg * 16 + srow;
            gload_lds16(A + (size_t)(mbase + row) * K + k0 + scol, (void*)(&As[bs][seg * 512]));
        }
        {
            int row = wid * 16 + srow;
            gload_lds16(B + (size_t)(nbase + row) * K + k0 + scol, (void*)(&Bs[bs][wid * 512]));
        }
    };

    stage(0, 0);
    __syncthreads();
    int buf = 0;
    for (int ks = 0; ks < nk; ++ks) {
        if (ks + 1 < nk) stage(buf ^ 1, (ks + 1) * BK);
        bf16x8 af[4], bfv[2];
#pragma unroll
        for (int i = 0; i < 4; i++)
            af[i] = *(const bf16x8*)(&As[buf][(wr * 64 + i * 16 + l15) * BK + l4 * 8]);
#pragma unroll
        for (int j = 0; j < 2; j++)
            bfv[j] = *(const bf16x8*)(&Bs[buf][(wc * 32 + j * 16 + l15) * BK + l4 * 8]);
#pragma unroll
        for (int i = 0; i < 4; i++)
#pragma unroll
            for (int j = 0; j < 2; j++)
                acc[i][j] = __builtin_amdgcn_mfma_f32_16x16x32_bf16(af[i], bfv[j], acc[i][j], 0, 0, 0);
        __syncthreads();
        buf ^= 1;
    }

#pragma unroll
    for (int i = 0; i < 4; i++)
#pragma unroll
        for (int j = 0; j < 2; j++)
#pragma unroll
            for (int r = 0; r < 4; r++) {
                int row = mbase + wr * 64 + i * 16 + l4 * 4 + r;
                int col = nbase + wc * 32 + j * 16 + l15;
                C[(size_t)row * N + col] = acc[i][j][r] + bias[col];
            }
}

// ---------------- attention ----------------
// T15 skew: QK[t] MFMAs issued, then exp/pack of tile t-1 (overlaps on VALU/TRANS),
// then PV[t-1] with V fragments loaded DIRECT from global (L2-resident) into regs.
__device__ __forceinline__ int invrow(int R) {  // logical LDS row -> klocal
    return 32 * (R >> 5) + 8 * ((R >> 2) & 3) + 4 * ((R >> 4) & 1) + (R & 3);
}

__global__ __launch_bounds__(256, 4)
void attn_kernel(const u16* __restrict__ Qb, const u16* __restrict__ Kb,
                 const u16* __restrict__ VT, u16* __restrict__ Ob)
{
    const int qt = blockIdx.x;   // 0..31
    const int bh = blockIdx.y;   // 0..31
    const int b = bh >> 4, h = bh & 15;
    __shared__ __align__(16) u16 Ks[2][4096];
    const int tid = threadIdx.x, wv = tid >> 6, lane = tid & 63;
    const int l15 = lane & 15, l4 = lane >> 4;

    const int r8 = lane >> 3;
    const int cp = lane & 7;
    const int cl = cp ^ r8;
    const int L0 = 2 * wv, L1 = 2 * wv + 1;
    const int RK0 = L0 * 8 + r8, RK1 = L1 * 8 + r8;
    const u16* ksrc0 = Kb + (size_t)(b * 2048 + invrow(RK0)) * 1024 + h * 64 + cl * 8;
    const u16* ksrc1 = Kb + (size_t)(b * 2048 + invrow(RK1)) * 1024 + h * 64 + cl * 8;

    // direct V fragment rows: frag(i,kk) of tile t = VT[(h*64+i*16+l15)][b*2048 + t*64 + (kk*4+l4)*8 ..+8]
    const u16* vrow0 = VT + (size_t)(h * 64 + l15) * 4096 + b * 2048 + l4 * 8;

    const u16* qrow = Qb + (size_t)(b * 2048 + qt * 64 + wv * 16 + l15) * 1024 + h * 64;
    bf16x8 qf0 = *(const bf16x8*)(qrow + l4 * 8);
    bf16x8 qf1 = *(const bf16x8*)(qrow + 32 + l4 * 8);

    const int swz = l15 & 7;
    const int q0o = (l4 ^ swz) * 8;
    const int q1o = ((4 + l4) ^ swz) * 8;

    f32x4 accO[4];
    float denom = 0.f;
#pragma unroll
    for (int i = 0; i < 4; i++) accO[i] = (f32x4){0.f, 0.f, 0.f, 0.f};

    auto stageK = [&](int bs, int kt) {
        gload_lds16(ksrc0 + (size_t)kt * 65536, (void*)&Ks[bs][L0 * 512]);
        gload_lds16(ksrc1 + (size_t)kt * 65536, (void*)&Ks[bs][L1 * 512]);
    };

    stageK(0, 0);
    __syncthreads();

    f32x4 sA[4], sB[4];
    bf16x8 vf[4][2];

    auto finish_tile = [&](f32x4 (&sold)[4]) {
        float p[4][4];
        float rs = 0.f;
#pragma unroll
        for (int j = 0; j < 4; j++)
#pragma unroll
            for (int r = 0; r < 4; r++) {
                p[j][r] = fexp2(sold[j][r]);
                rs += p[j][r];
            }
        rs += __shfl_xor(rs, 16);
        rs += __shfl_xor(rs, 32);
        denom += rs;
        union { uint32_t u[4]; bf16x8 v; } B0u, B1u;
        B0u.u[0] = cvt_pk_bf16(p[0][0], p[0][1]);
        B0u.u[1] = cvt_pk_bf16(p[0][2], p[0][3]);
        B0u.u[2] = cvt_pk_bf16(p[1][0], p[1][1]);
        B0u.u[3] = cvt_pk_bf16(p[1][2], p[1][3]);
        B1u.u[0] = cvt_pk_bf16(p[2][0], p[2][1]);
        B1u.u[1] = cvt_pk_bf16(p[2][2], p[2][3]);
        B1u.u[2] = cvt_pk_bf16(p[3][0], p[3][1]);
        B1u.u[3] = cvt_pk_bf16(p[3][2], p[3][3]);
        __builtin_amdgcn_s_setprio(1);
#pragma unroll
        for (int i = 0; i < 4; i++) {
            accO[i] = __builtin_amdgcn_mfma_f32_16x16x32_bf16(vf[i][0], B0u.v, accO[i], 0, 0, 0);
            accO[i] = __builtin_amdgcn_mfma_f32_16x16x32_bf16(vf[i][1], B1u.v, accO[i], 0, 0, 0);
        }
        __builtin_amdgcn_s_setprio(0);
    };

    auto body = [&](int kt, f32x4 (&snew)[4], f32x4 (&sold)[4]) {
        // V fragments for tile kt-1 -> registers (L2-resident; compiler inserts vmcnt)
        if (kt > 0) {
            const u16* vp = vrow0 + (size_t)(kt - 1) * 64;
#pragma unroll
            for (int i = 0; i < 4; i++) {
                vf[i][0] = *(const bf16x8*)(vp + (size_t)i * 16 * 4096);
                vf[i][1] = *(const bf16x8*)(vp + (size_t)i * 16 * 4096 + 32);
            }
        }
        // QK[kt] (MFMA pipe; exp/pack below overlaps)
#pragma unroll
        for (int j = 0; j < 4; j++) snew[j] = (f32x4){0.f, 0.f, 0.f, 0.f};
        const int kb = kt & 1;
        __builtin_amdgcn_s_setprio(1);
#pragma unroll
        for (int j = 0; j < 4; j++) {
            const u16* rp = &Ks[kb][(j * 16 + l15) * 64];
            bf16x8 a0 = *(const bf16x8*)(rp + q0o);
            bf16x8 a1 = *(const bf16x8*)(rp + q1o);
            snew[j] = __builtin_amdgcn_mfma_f32_16x16x32_bf16(a0, qf0, snew[j], 0, 0, 0);
            snew[j] = __builtin_amdgcn_mfma_f32_16x16x32_bf16(a1, qf1, snew[j], 0, 0, 0);
        }
        __builtin_amdgcn_s_setprio(0);
        if (kt < 31) stageK(kb ^ 1, kt + 1);
        if (kt > 0) finish_tile(sold);
        __syncthreads();
    };

    for (int kt2 = 0; kt2 < 32; kt2 += 2) {
        body(kt2, sA, sB);
        body(kt2 + 1, sB, sA);
    }
    // epilogue: tile 31 (s in sB)
    {
        const u16* vp = vrow0 + (size_t)31 * 64;
#pragma unroll
        for (int i = 0; i < 4; i++) {
            vf[i][0] = *(const bf16x8*)(vp + (size_t)i * 16 * 4096);
            vf[i][1] = *(const bf16x8*)(vp + (size_t)i * 16 * 4096 + 32);
        }
        finish_tile(sB);
    }

    float rd = 1.0f / denom;
    u16* orow = Ob + (size_t)(b * 2048 + qt * 64 + wv * 16 + l15) * 1024 + h * 64;
#pragma unroll
    for (int i = 0; i < 4; i++) {
        uint2 st;
        st.x = cvt_pk_bf16(accO[i][0] * rd, accO[i][1] * rd);
        st.y = cvt_pk_bf16(accO[i][2] * rd, accO[i][3] * rd);
        *(uint2*)(orow + i * 16 + l4 * 4) = st;
    }
}

extern "C" void kernel_launch(void* const* d_in, const int* in_sizes, int n_in,
                              void* d_out, int out_size, void* d_ws, size_t ws_size,
                              hipStream_t stream) {
    const float* x   = (const float*)d_in[0];
    const float* ctx = (const float*)d_in[1];
    const float* Wq  = (const float*)d_in[2];
    const float* bq  = (const float*)d_in[3];
    const float* Wk  = (const float*)d_in[4];
    const float* bk  = (const float*)d_in[5];
    const float* Wv  = (const float*)d_in[6];
    const float* bv  = (const float*)d_in[7];
    const float* Wo  = (const float*)d_in[8];
    const float* bo  = (const float*)d_in[9];
    float* out = (float*)d_out;

    char* ws = (char*)d_ws;
    size_t off = 0;
    auto alloc = [&](size_t bytes) { void* p = ws + off; off += (bytes + 255) & ~255ULL; return p; };
    u16* x_bf  = (u16*)alloc(4096ULL * 1024 * 2);
    u16* c_bf  = (u16*)alloc(4096ULL * 1152 * 2);
    u16* wq_bf = (u16*)alloc(1024ULL * 1024 * 2);
    u16* wk_bf = (u16*)alloc(1024ULL * 1152 * 2);
    u16* wv_bf = (u16*)alloc(1024ULL * 1152 * 2);
    u16* wo_bf = (u16*)alloc(1024ULL * 1024 * 2);
    float2* cs = (float2*)alloc(2048ULL * 32 * 8);
    u16* q_bf  = (u16*)alloc(4096ULL * 1024 * 2);
    u16* k_bf  = (u16*)alloc(4096ULL * 1024 * 2);
    u16* vT    = (u16*)alloc(1024ULL * 4096 * 2);
    u16* a_bf  = (u16*)alloc(4096ULL * 1024 * 2);

    prep_kernel<<<13312, 256, 0, stream>>>(x, ctx, Wq, Wk, Wv, Wo,
                                           x_bf, c_bf, wq_bf, wk_bf, wv_bf, wo_bf, cs);
    qkv_gemm<<<768, 256, 0, stream>>>(x_bf, c_bf, wq_bf, wk_bf, wv_bf,
                                      bq, bk, bv, q_bf, k_bf, vT, cs);
    attn_kernel<<<dim3(32, 32), 256, 0, stream>>>(q_bf, k_bf, vT, a_bf);
    gemm_out<<<dim3(16, 32), 256, 0, stream>>>(a_bf, wo_bf, bo, out, 4096, 1024, 1024);
}

// Round 18
// 135.015 us; speedup vs baseline: 1.6195x; 1.6195x over previous
//
#include <hip/hip_runtime.h>
#include <hip/hip_bf16.h>
#include <stdint.h>

typedef unsigned short u16;
typedef __attribute__((ext_vector_type(8))) short bf16x8;
typedef __attribute__((ext_vector_type(8))) unsigned short u16x8;
typedef __attribute__((ext_vector_type(4))) float f32x4;

#define BM 128
#define BN 128
#define BK 32
#define QBK 64
// folded into Q at projection: softmax scale 1/8 times log2(e)
#define QSCALE 0.18033688f

__device__ __forceinline__ u16 f2bf(float f) {
    union { float f; uint32_t u; } v; v.f = f;
    uint32_t r = v.u + 0x7FFFu + ((v.u >> 16) & 1u);
    return (u16)(r >> 16);
}

__device__ __forceinline__ uint32_t cvt_pk_bf16(float lo, float hi) {
    uint32_t r;
    asm("v_cvt_pk_bf16_f32 %0, %1, %2" : "=v"(r) : "v"(lo), "v"(hi));
    return r;
}

// raw 2^x; s_nop covers the TRANS->VALU hazard for the consumer
__device__ __forceinline__ float fexp2(float x) {
    float r;
    asm volatile("v_exp_f32 %0, %1\n\ts_nop 0" : "=v"(r) : "v"(x));
    return r;
}

__device__ __forceinline__ void gload_lds16(const void* g, void* l) {
    __builtin_amdgcn_global_load_lds(
        (const __attribute__((address_space(1))) void*)(g),
        (__attribute__((address_space(3))) void*)(l),
        16, 0, 0);
}

// ---------------- fused prep: 6 casts + rope table ----------------
__global__ void prep_kernel(const float* __restrict__ x, const float* __restrict__ ctx,
                            const float* __restrict__ Wq, const float* __restrict__ Wk,
                            const float* __restrict__ Wv, const float* __restrict__ Wo,
                            u16* __restrict__ xb, u16* __restrict__ cb,
                            u16* __restrict__ wqb, u16* __restrict__ wkb,
                            u16* __restrict__ wvb, u16* __restrict__ wob,
                            float2* __restrict__ cs) {
    int t = blockIdx.x * 256 + threadIdx.x;
    if (t < 3342336) {
        const float* src; u16* dst; int base;
        if      (t < 1048576) { src = x;   dst = xb;  base = 0; }
        else if (t < 2228224) { src = ctx; dst = cb;  base = 1048576; }
        else if (t < 2490368) { src = Wq;  dst = wqb; base = 2228224; }
        else if (t < 2785280) { src = Wk;  dst = wkb; base = 2490368; }
        else if (t < 3080192) { src = Wv;  dst = wvb; base = 2785280; }
        else                  { src = Wo;  dst = wob; base = 3080192; }
        int i = (t - base) * 4;
        float4 v = *reinterpret_cast<const float4*>(src + i);
        ushort4 o = { f2bf(v.x), f2bf(v.y), f2bf(v.z), f2bf(v.w) };
        *reinterpret_cast<ushort4*>(dst + i) = o;
    } else {
        int idx = t - 3342336;           // 0..65535
        int tt = idx >> 5, j = idx & 31;
        float invf = 1.0f / powf(10000.0f, (float)(2 * j) / 64.0f);
        float ang = (float)tt * invf;
        cs[idx] = make_float2(cosf(ang), sinf(ang));
    }
}

// ---------------- fused Q/K/V projection GEMM ----------------
// 128x128 tile, BK=64, 768 blocks = 3/CU, XCD swizzle, single-buffer 32KB LDS,
// XOR-swizzled 128B rows.
__global__ __launch_bounds__(256, 3)
void qkv_gemm(const u16* __restrict__ xb, const u16* __restrict__ cb,
              const u16* __restrict__ wqb, const u16* __restrict__ wkb,
              const u16* __restrict__ wvb,
              const float* __restrict__ bq, const float* __restrict__ bk,
              const float* __restrict__ bv,
              u16* __restrict__ qo, u16* __restrict__ ko, u16* __restrict__ vo,
              const float2* __restrict__ cs)
{
    __shared__ __align__(16) u16 As[BM * QBK];   // 16 KB
    __shared__ __align__(16) u16 Bs[BN * QBK];   // 16 KB
    const int bid = blockIdx.x;
    const int wg = (bid & 7) * 96 + (bid >> 3);
    const int seg = wg >> 8, inner = wg & 255;
    const u16* A; const u16* Bm; const float* bias; u16* C;
    int N, K, mbase, nbase, rope, brow;
    float oscale;
    if (seg == 0)      { A = xb;  Bm = wqb; bias = bq; C = qo; N = 1024; K = 1024; rope = 1; brow = 0; oscale = QSCALE; nbase = (inner & 7) * BN;  mbase = (inner >> 3) * BM; }
    else if (seg == 1) { A = cb;  Bm = wkb; bias = bk; C = ko; N = 1024; K = 1152; rope = 1; brow = 0; oscale = 1.0f;   nbase = (inner & 7) * BN;  mbase = (inner >> 3) * BM; }
    else               { A = wvb; Bm = cb;  bias = bv; C = vo; N = 4096; K = 1152; rope = 0; brow = 1; oscale = 1.0f;   nbase = (inner & 31) * BN; mbase = (inner >> 5) * BM; }

    const int tid = threadIdx.x;
    const int wid = tid >> 6, lane = tid & 63;
    const int wr = wid >> 1, wc = wid & 1;
    const int l15 = lane & 15, l4 = lane >> 4;
    const int r8 = lane >> 3;
    const int cp = lane & 7;
    const int cl = cp ^ r8;

    f32x4 acc[4][4];
#pragma unroll
    for (int i = 0; i < 4; i++)
#pragma unroll
        for (int j = 0; j < 4; j++) acc[i][j] = (f32x4){0.f, 0.f, 0.f, 0.f};

    for (int k0 = 0; k0 < K; k0 += QBK) {
#pragma unroll
        for (int q = 0; q < 4; ++q) {
            int sg = wid * 4 + q;
            int row = sg * 8 + r8;
            gload_lds16(A  + (size_t)(mbase + row) * K + k0 + cl * 8, (void*)(As + sg * 512));
            gload_lds16(Bm + (size_t)(nbase + row) * K + k0 + cl * 8, (void*)(Bs + sg * 512));
        }
        __syncthreads();
        bf16x8 af[2][4], bfv[2][4];
#pragma unroll
        for (int kk = 0; kk < 2; kk++) {
#pragma unroll
            for (int i = 0; i < 4; i++) {
                int r = wr * 64 + i * 16 + l15;
                af[kk][i] = *(const bf16x8*)(As + r * 64 + (((kk * 4 + l4) ^ (r & 7)) * 8));
            }
#pragma unroll
            for (int j = 0; j < 4; j++) {
                int r = wc * 64 + j * 16 + l15;
                bfv[kk][j] = *(const bf16x8*)(Bs + r * 64 + (((kk * 4 + l4) ^ (r & 7)) * 8));
            }
        }
        __builtin_amdgcn_s_setprio(1);
#pragma unroll
        for (int kk = 0; kk < 2; kk++)
#pragma unroll
            for (int i = 0; i < 4; i++)
#pragma unroll
                for (int j = 0; j < 4; j++)
                    acc[i][j] = __builtin_amdgcn_mfma_f32_16x16x32_bf16(af[kk][i], bfv[kk][j], acc[i][j], 0, 0, 0);
        __builtin_amdgcn_s_setprio(0);
        __syncthreads();
    }

#pragma unroll
    for (int i = 0; i < 4; i++) {
#pragma unroll
        for (int j = 0; j < 4; j++) {
#pragma unroll
            for (int r = 0; r < 4; r++) {
                int row = mbase + wr * 64 + i * 16 + l4 * 4 + r;
                int col = nbase + wc * 64 + j * 16 + l15;
                float v = acc[i][j][r] + (brow ? bias[row] : bias[col]);
                if (rope) {
                    float part = __shfl_xor(v, 1);
                    float2 c2 = cs[(row & 2047) * 32 + (col & 31)];
                    v = v * c2.x + ((col & 1) ? part * c2.y : -part * c2.y);
                    v *= oscale;
                }
                C[(size_t)row * N + col] = f2bf(v);
            }
        }
    }
}

// ---------------- O-projection GEMM: out = attn @ Wo^T + bo (f32 out) ----------------
__global__ __launch_bounds__(256, 2)
void gemm_out(const u16* __restrict__ A, const u16* __restrict__ B,
              const float* __restrict__ bias, float* __restrict__ C,
              int M, int N, int K)
{
    __shared__ __align__(16) u16 As[2][BM * BK];
    __shared__ __align__(16) u16 Bs[2][64 * BK];
    const int tid = threadIdx.x;
    const int wid = tid >> 6, lane = tid & 63;
    const int wr = wid >> 1, wc = wid & 1;
    const int l15 = lane & 15, l4 = lane >> 4;
    const int mbase = blockIdx.y * BM, nbase = blockIdx.x * 64;
    const int srow = lane >> 2;
    const int scol = (lane & 3) * 8;
    const int nk = K >> 5;

    f32x4 acc[4][2];
#pragma unroll
    for (int i = 0; i < 4; i++)
#pragma unroll
        for (int j = 0; j < 2; j++) acc[i][j] = (f32x4){0.f, 0.f, 0.f, 0.f};

    auto stage = [&](int bs, int k0) {
#pragma unroll
        for (int q = 0; q < 2; ++q) {
            int seg = wid * 2 + q;
            int row = seg * 16 + srow;
            gload_lds16(A + (size_t)(mbase + row) * K + k0 + scol, (void*)(&As[bs][seg * 512]));
        }
        {
            int row = wid * 16 + srow;
            gload_lds16(B + (size_t)(nbase + row) * K + k0 + scol, (void*)(&Bs[bs][wid * 512]));
        }
    };

    stage(0, 0);
    __syncthreads();
    int buf = 0;
    for (int ks = 0; ks < nk; ++ks) {
        if (ks + 1 < nk) stage(buf ^ 1, (ks + 1) * BK);
        bf16x8 af[4], bfv[2];
#pragma unroll
        for (int i = 0; i < 4; i++)
            af[i] = *(const bf16x8*)(&As[buf][(wr * 64 + i * 16 + l15) * BK + l4 * 8]);
#pragma unroll
        for (int j = 0; j < 2; j++)
            bfv[j] = *(const bf16x8*)(&Bs[buf][(wc * 32 + j * 16 + l15) * BK + l4 * 8]);
#pragma unroll
        for (int i = 0; i < 4; i++)
#pragma unroll
            for (int j = 0; j < 2; j++)
                acc[i][j] = __builtin_amdgcn_mfma_f32_16x16x32_bf16(af[i], bfv[j], acc[i][j], 0, 0, 0);
        __syncthreads();
        buf ^= 1;
    }

#pragma unroll
    for (int i = 0; i < 4; i++)
#pragma unroll
        for (int j = 0; j < 2; j++)
#pragma unroll
            for (int r = 0; r < 4; r++) {
                int row = mbase + wr * 64 + i * 16 + l4 * 4 + r;
                int col = nbase + wc * 32 + j * 16 + l15;
                C[(size_t)row * N + col] = acc[i][j][r] + bias[col];
            }
}

// ---------------- attention ----------------
// T15 skew with LAGGED cooperative V staging: body(t) = QK[t] MFMAs (Ks[t&1]),
// stage K[t+1]->Ks[t&1^1] and V[t]->Vs[t&1^1], then exp/pack/PV of tile t-1
// (Vs[t&1]) overlapping the in-flight QK MFMAs; one barrier per tile.
__device__ __forceinline__ int invrow(int R) {  // logical LDS row -> klocal
    return 32 * (R >> 5) + 8 * ((R >> 2) & 3) + 4 * ((R >> 4) & 1) + (R & 3);
}

__global__ __launch_bounds__(256, 4)
void attn_kernel(const u16* __restrict__ Qb, const u16* __restrict__ Kb,
                 const u16* __restrict__ VT, u16* __restrict__ Ob)
{
    const int qt = blockIdx.x;   // 0..31
    const int bh = blockIdx.y;   // 0..31
    const int b = bh >> 4, h = bh & 15;
    __shared__ __align__(16) u16 Ks[2][4096];
    __shared__ __align__(16) u16 Vs[2][4096];
    const int tid = threadIdx.x, wv = tid >> 6, lane = tid & 63;
    const int l15 = lane & 15, l4 = lane >> 4;

    const int r8 = lane >> 3;
    const int cp = lane & 7;
    const int cl = cp ^ r8;
    const int L0 = 2 * wv, L1 = 2 * wv + 1;
    const int RK0 = L0 * 8 + r8, RK1 = L1 * 8 + r8;
    const u16* ksrc0 = Kb + (size_t)(b * 2048 + invrow(RK0)) * 1024 + h * 64 + cl * 8;
    const u16* ksrc1 = Kb + (size_t)(b * 2048 + invrow(RK1)) * 1024 + h * 64 + cl * 8;
    const u16* vsrc0 = VT + (size_t)(h * 64 + RK0) * 4096 + b * 2048 + cl * 8;
    const u16* vsrc1 = VT + (size_t)(h * 64 + RK1) * 4096 + b * 2048 + cl * 8;

    const u16* qrow = Qb + (size_t)(b * 2048 + qt * 64 + wv * 16 + l15) * 1024 + h * 64;
    bf16x8 qf0 = *(const bf16x8*)(qrow + l4 * 8);
    bf16x8 qf1 = *(const bf16x8*)(qrow + 32 + l4 * 8);

    const int swz = l15 & 7;
    const int q0o = (l4 ^ swz) * 8;
    const int q1o = ((4 + l4) ^ swz) * 8;

    f32x4 accO[4];
    float denom = 0.f;
#pragma unroll
    for (int i = 0; i < 4; i++) accO[i] = (f32x4){0.f, 0.f, 0.f, 0.f};

    auto stageK = [&](int bs, int kt) {
        gload_lds16(ksrc0 + (size_t)kt * 65536, (void*)&Ks[bs][L0 * 512]);
        gload_lds16(ksrc1 + (size_t)kt * 65536, (void*)&Ks[bs][L1 * 512]);
    };
    auto stageV = [&](int bs, int kt) {
        gload_lds16(vsrc0 + kt * 64, (void*)&Vs[bs][L0 * 512]);
        gload_lds16(vsrc1 + kt * 64, (void*)&Vs[bs][L1 * 512]);
    };

    stageK(0, 0);
    __syncthreads();

    f32x4 sA[4], sB[4];

    auto finish_tile = [&](f32x4 (&sold)[4], int vbuf) {
        float p[4][4];
        float rs = 0.f;
#pragma unroll
        for (int j = 0; j < 4; j++)
#pragma unroll
            for (int r = 0; r < 4; r++) {
                p[j][r] = fexp2(sold[j][r]);
                rs += p[j][r];
            }
        rs += __shfl_xor(rs, 16);
        rs += __shfl_xor(rs, 32);
        denom += rs;
        union { uint32_t u[4]; bf16x8 v; } B0u, B1u;
        B0u.u[0] = cvt_pk_bf16(p[0][0], p[0][1]);
        B0u.u[1] = cvt_pk_bf16(p[0][2], p[0][3]);
        B0u.u[2] = cvt_pk_bf16(p[1][0], p[1][1]);
        B0u.u[3] = cvt_pk_bf16(p[1][2], p[1][3]);
        B1u.u[0] = cvt_pk_bf16(p[2][0], p[2][1]);
        B1u.u[1] = cvt_pk_bf16(p[2][2], p[2][3]);
        B1u.u[2] = cvt_pk_bf16(p[3][0], p[3][1]);
        B1u.u[3] = cvt_pk_bf16(p[3][2], p[3][3]);
        __builtin_amdgcn_s_setprio(1);
#pragma unroll
        for (int i = 0; i < 4; i++) {
            const u16* vp = &Vs[vbuf][(i * 16 + l15) * 64];
            bf16x8 v0 = *(const bf16x8*)(vp + q0o);
            bf16x8 v1 = *(const bf16x8*)(vp + q1o);
            accO[i] = __builtin_amdgcn_mfma_f32_16x16x32_bf16(v0, B0u.v, accO[i], 0, 0, 0);
            accO[i] = __builtin_amdgcn_mfma_f32_16x16x32_bf16(v1, B1u.v, accO[i], 0, 0, 0);
        }
        __builtin_amdgcn_s_setprio(0);
    };

    auto body = [&](int kt, f32x4 (&snew)[4], f32x4 (&sold)[4]) {
        const int kb = kt & 1;
        // QK[kt] (MFMA pipe; finish_tile below overlaps on TRANS/VALU)
#pragma unroll
        for (int j = 0; j < 4; j++) snew[j] = (f32x4){0.f, 0.f, 0.f, 0.f};
        __builtin_amdgcn_s_setprio(1);
#pragma unroll
        for (int j = 0; j < 4; j++) {
            const u16* rp = &Ks[kb][(j * 16 + l15) * 64];
            bf16x8 a0 = *(const bf16x8*)(rp + q0o);
            bf16x8 a1 = *(const bf16x8*)(rp + q1o);
            snew[j] = __builtin_amdgcn_mfma_f32_16x16x32_bf16(a0, qf0, snew[j], 0, 0, 0);
            snew[j] = __builtin_amdgcn_mfma_f32_16x16x32_bf16(a1, qf1, snew[j], 0, 0, 0);
        }
        __builtin_amdgcn_s_setprio(0);
        // lagged staging: K[kt+1] and V[kt] into the other buffer
        if (kt < 31) stageK(kb ^ 1, kt + 1);
        stageV(kb ^ 1, kt);
        // exp/pack/PV of tile kt-1 (independent of in-flight QK MFMAs)
        if (kt > 0) finish_tile(sold, kb);
        __syncthreads();
    };

    for (int kt2 = 0; kt2 < 32; kt2 += 2) {
        body(kt2, sA, sB);
        body(kt2 + 1, sB, sA);
    }
    // epilogue: tile 31 (s in sB, V[31] staged into buffer 0)
    finish_tile(sB, 0);

    float rd = 1.0f / denom;
    u16* orow = Ob + (size_t)(b * 2048 + qt * 64 + wv * 16 + l15) * 1024 + h * 64;
#pragma unroll
    for (int i = 0; i < 4; i++) {
        uint2 st;
        st.x = cvt_pk_bf16(accO[i][0] * rd, accO[i][1] * rd);
        st.y = cvt_pk_bf16(accO[i][2] * rd, accO[i][3] * rd);
        *(uint2*)(orow + i * 16 + l4 * 4) = st;
    }
}

extern "C" void kernel_launch(void* const* d_in, const int* in_sizes, int n_in,
                              void* d_out, int out_size, void* d_ws, size_t ws_size,
                              hipStream_t stream) {
    const float* x   = (const float*)d_in[0];
    const float* ctx = (const float*)d_in[1];
    const float* Wq  = (const float*)d_in[2];
    const float* bq  = (const float*)d_in[3];
    const float* Wk  = (const float*)d_in[4];
    const float* bk  = (const float*)d_in[5];
    const float* Wv  = (const float*)d_in[6];
    const float* bv  = (const float*)d_in[7];
    const float* Wo  = (const float*)d_in[8];
    const float* bo  = (const float*)d_in[9];
    float* out = (float*)d_out;

    char* ws = (char*)d_ws;
    size_t off = 0;
    auto alloc = [&](size_t bytes) { void* p = ws + off; off += (bytes + 255) & ~255ULL; return p; };
    u16* x_bf  = (u16*)alloc(4096ULL * 1024 * 2);
    u16* c_bf  = (u16*)alloc(4096ULL * 1152 * 2);
    u16* wq_bf = (u16*)alloc(1024ULL * 1024 * 2);
    u16* wk_bf = (u16*)alloc(1024ULL * 1152 * 2);
    u16* wv_bf = (u16*)alloc(1024ULL * 1152 * 2);
    u16* wo_bf = (u16*)alloc(1024ULL * 1024 * 2);
    float2* cs = (float2*)alloc(2048ULL * 32 * 8);
    u16* q_bf  = (u16*)alloc(4096ULL * 1024 * 2);
    u16* k_bf  = (u16*)alloc(4096ULL * 1024 * 2);
    u16* vT    = (u16*)alloc(1024ULL * 4096 * 2);
    u16* a_bf  = (u16*)alloc(4096ULL * 1024 * 2);

    prep_kernel<<<13312, 256, 0, stream>>>(x, ctx, Wq, Wk, Wv, Wo,
                                           x_bf, c_bf, wq_bf, wk_bf, wv_bf, wo_bf, cs);
    qkv_gemm<<<768, 256, 0, stream>>>(x_bf, c_bf, wq_bf, wk_bf, wv_bf,
                                      bq, bk, bv, q_bf, k_bf, vT, cs);
    attn_kernel<<<dim3(32, 32), 256, 0, stream>>>(q_bf, k_bf, vT, a_bf);
    gemm_out<<<dim3(16, 32), 256, 0, stream>>>(a_bf, wo_bf, bo, out, 4096, 1024, 1024);
}

// Round 19
// 125.899 us; speedup vs baseline: 1.7368x; 1.0724x over previous
//
#include <hip/hip_runtime.h>
#include <hip/hip_bf16.h>
#include <stdint.h>

typedef unsigned short u16;
typedef __attribute__((ext_vector_type(8))) short bf16x8;
typedef __attribute__((ext_vector_type(8))) unsigned short u16x8;
typedef __attribute__((ext_vector_type(4))) float f32x4;

#define BM 128
#define BN 128
#define BK 32
#define QBK 64
// folded into Q at projection: softmax scale 1/8 times log2(e)
#define QSCALE 0.18033688f

__device__ __forceinline__ u16 f2bf(float f) {
    union { float f; uint32_t u; } v; v.f = f;
    uint32_t r = v.u + 0x7FFFu + ((v.u >> 16) & 1u);
    return (u16)(r >> 16);
}

__device__ __forceinline__ uint32_t cvt_pk_bf16(float lo, float hi) {
    uint32_t r;
    asm("v_cvt_pk_bf16_f32 %0, %1, %2" : "=v"(r) : "v"(lo), "v"(hi));
    return r;
}

// raw 2^x; s_nop covers the TRANS->VALU hazard for the consumer
__device__ __forceinline__ float fexp2(float x) {
    float r;
    asm volatile("v_exp_f32 %0, %1\n\ts_nop 0" : "=v"(r) : "v"(x));
    return r;
}

__device__ __forceinline__ void gload_lds16(const void* g, void* l) {
    __builtin_amdgcn_global_load_lds(
        (const __attribute__((address_space(1))) void*)(g),
        (__attribute__((address_space(3))) void*)(l),
        16, 0, 0);
}

// ---------------- fused prep: 6 casts + rope table ----------------
__global__ void prep_kernel(const float* __restrict__ x, const float* __restrict__ ctx,
                            const float* __restrict__ Wq, const float* __restrict__ Wk,
                            const float* __restrict__ Wv, const float* __restrict__ Wo,
                            u16* __restrict__ xb, u16* __restrict__ cb,
                            u16* __restrict__ wqb, u16* __restrict__ wkb,
                            u16* __restrict__ wvb, u16* __restrict__ wob,
                            float2* __restrict__ cs) {
    int t = blockIdx.x * 256 + threadIdx.x;
    if (t < 3342336) {
        const float* src; u16* dst; int base;
        if      (t < 1048576) { src = x;   dst = xb;  base = 0; }
        else if (t < 2228224) { src = ctx; dst = cb;  base = 1048576; }
        else if (t < 2490368) { src = Wq;  dst = wqb; base = 2228224; }
        else if (t < 2785280) { src = Wk;  dst = wkb; base = 2490368; }
        else if (t < 3080192) { src = Wv;  dst = wvb; base = 2785280; }
        else                  { src = Wo;  dst = wob; base = 3080192; }
        int i = (t - base) * 4;
        float4 v = *reinterpret_cast<const float4*>(src + i);
        ushort4 o = { f2bf(v.x), f2bf(v.y), f2bf(v.z), f2bf(v.w) };
        *reinterpret_cast<ushort4*>(dst + i) = o;
    } else {
        int idx = t - 3342336;           // 0..65535
        int tt = idx >> 5, j = idx & 31;
        float invf = 1.0f / powf(10000.0f, (float)(2 * j) / 64.0f);
        float ang = (float)tt * invf;
        cs[idx] = make_float2(cosf(ang), sinf(ang));
    }
}

// ---------------- fused Q/K/V projection GEMM ----------------
// 128x128 tile, BK=64, 768 blocks = 3/CU, XCD swizzle, single-buffer 32KB LDS,
// XOR-swizzled 128B rows.
__global__ __launch_bounds__(256, 3)
void qkv_gemm(const u16* __restrict__ xb, const u16* __restrict__ cb,
              const u16* __restrict__ wqb, const u16* __restrict__ wkb,
              const u16* __restrict__ wvb,
              const float* __restrict__ bq, const float* __restrict__ bk,
              const float* __restrict__ bv,
              u16* __restrict__ qo, u16* __restrict__ ko, u16* __restrict__ vo,
              const float2* __restrict__ cs)
{
    __shared__ __align__(16) u16 As[BM * QBK];   // 16 KB
    __shared__ __align__(16) u16 Bs[BN * QBK];   // 16 KB
    const int bid = blockIdx.x;
    const int wg = (bid & 7) * 96 + (bid >> 3);
    const int seg = wg >> 8, inner = wg & 255;
    const u16* A; const u16* Bm; const float* bias; u16* C;
    int N, K, mbase, nbase, rope, brow;
    float oscale;
    if (seg == 0)      { A = xb;  Bm = wqb; bias = bq; C = qo; N = 1024; K = 1024; rope = 1; brow = 0; oscale = QSCALE; nbase = (inner & 7) * BN;  mbase = (inner >> 3) * BM; }
    else if (seg == 1) { A = cb;  Bm = wkb; bias = bk; C = ko; N = 1024; K = 1152; rope = 1; brow = 0; oscale = 1.0f;   nbase = (inner & 7) * BN;  mbase = (inner >> 3) * BM; }
    else               { A = wvb; Bm = cb;  bias = bv; C = vo; N = 4096; K = 1152; rope = 0; brow = 1; oscale = 1.0f;   nbase = (inner & 31) * BN; mbase = (inner >> 5) * BM; }

    const int tid = threadIdx.x;
    const int wid = tid >> 6, lane = tid & 63;
    const int wr = wid >> 1, wc = wid & 1;
    const int l15 = lane & 15, l4 = lane >> 4;
    const int r8 = lane >> 3;
    const int cp = lane & 7;
    const int cl = cp ^ r8;

    f32x4 acc[4][4];
#pragma unroll
    for (int i = 0; i < 4; i++)
#pragma unroll
        for (int j = 0; j < 4; j++) acc[i][j] = (f32x4){0.f, 0.f, 0.f, 0.f};

    for (int k0 = 0; k0 < K; k0 += QBK) {
#pragma unroll
        for (int q = 0; q < 4; ++q) {
            int sg = wid * 4 + q;
            int row = sg * 8 + r8;
            gload_lds16(A  + (size_t)(mbase + row) * K + k0 + cl * 8, (void*)(As + sg * 512));
            gload_lds16(Bm + (size_t)(nbase + row) * K + k0 + cl * 8, (void*)(Bs + sg * 512));
        }
        __syncthreads();
        bf16x8 af[2][4], bfv[2][4];
#pragma unroll
        for (int kk = 0; kk < 2; kk++) {
#pragma unroll
            for (int i = 0; i < 4; i++) {
                int r = wr * 64 + i * 16 + l15;
                af[kk][i] = *(const bf16x8*)(As + r * 64 + (((kk * 4 + l4) ^ (r & 7)) * 8));
            }
#pragma unroll
            for (int j = 0; j < 4; j++) {
                int r = wc * 64 + j * 16 + l15;
                bfv[kk][j] = *(const bf16x8*)(Bs + r * 64 + (((kk * 4 + l4) ^ (r & 7)) * 8));
            }
        }
        __builtin_amdgcn_s_setprio(1);
#pragma unroll
        for (int kk = 0; kk < 2; kk++)
#pragma unroll
            for (int i = 0; i < 4; i++)
#pragma unroll
                for (int j = 0; j < 4; j++)
                    acc[i][j] = __builtin_amdgcn_mfma_f32_16x16x32_bf16(af[kk][i], bfv[kk][j], acc[i][j], 0, 0, 0);
        __builtin_amdgcn_s_setprio(0);
        __syncthreads();
    }

#pragma unroll
    for (int i = 0; i < 4; i++) {
#pragma unroll
        for (int j = 0; j < 4; j++) {
#pragma unroll
            for (int r = 0; r < 4; r++) {
                int row = mbase + wr * 64 + i * 16 + l4 * 4 + r;
                int col = nbase + wc * 64 + j * 16 + l15;
                float v = acc[i][j][r] + (brow ? bias[row] : bias[col]);
                if (rope) {
                    float part = __shfl_xor(v, 1);
                    float2 c2 = cs[(row & 2047) * 32 + (col & 31)];
                    v = v * c2.x + ((col & 1) ? part * c2.y : -part * c2.y);
                    v *= oscale;
                }
                C[(size_t)row * N + col] = f2bf(v);
            }
        }
    }
}

// ---------------- O-projection GEMM: out = attn @ Wo^T + bo (f32 out) ----------------
// 128x64 tile, BK=64 (qkv recipe), single-buffer 24KB, XOR-swizzled rows,
// grid (16,32) = 512 blocks.
__global__ __launch_bounds__(256, 2)
void gemm_out(const u16* __restrict__ A, const u16* __restrict__ B,
              const float* __restrict__ bias, float* __restrict__ C,
              int M, int N, int K)
{
    __shared__ __align__(16) u16 As[BM * QBK];   // 16 KB
    __shared__ __align__(16) u16 Bs[64 * QBK];   // 8 KB
    const int tid = threadIdx.x;
    const int wid = tid >> 6, lane = tid & 63;
    const int wr = wid >> 1, wc = wid & 1;       // wave tile: 64m x 32n
    const int l15 = lane & 15, l4 = lane >> 4;
    const int mbase = blockIdx.y * BM, nbase = blockIdx.x * 64;
    const int r8 = lane >> 3;
    const int cp = lane & 7;
    const int cl = cp ^ r8;

    f32x4 acc[4][2];
#pragma unroll
    for (int i = 0; i < 4; i++)
#pragma unroll
        for (int j = 0; j < 2; j++) acc[i][j] = (f32x4){0.f, 0.f, 0.f, 0.f};

    for (int k0 = 0; k0 < K; k0 += QBK) {
#pragma unroll
        for (int q = 0; q < 4; ++q) {
            int sg = wid * 4 + q;                // 0..15: 128 A rows
            int row = sg * 8 + r8;
            gload_lds16(A + (size_t)(mbase + row) * K + k0 + cl * 8, (void*)(As + sg * 512));
        }
        {
            int sg = wid * 2 + (lane >> 5);     // 0..7 covers 64 B rows (2 sub-half-waves)
        }
#pragma unroll
        for (int q = 0; q < 2; ++q) {
            int sg = wid * 2 + q;                // 0..7: 64 B rows
            int row = sg * 8 + r8;
            gload_lds16(B + (size_t)(nbase + row) * K + k0 + cl * 8, (void*)(Bs + sg * 512));
        }
        __syncthreads();
        bf16x8 af[2][4], bfv[2][2];
#pragma unroll
        for (int kk = 0; kk < 2; kk++) {
#pragma unroll
            for (int i = 0; i < 4; i++) {
                int r = wr * 64 + i * 16 + l15;
                af[kk][i] = *(const bf16x8*)(As + r * 64 + (((kk * 4 + l4) ^ (r & 7)) * 8));
            }
#pragma unroll
            for (int j = 0; j < 2; j++) {
                int r = wc * 32 + j * 16 + l15;
                bfv[kk][j] = *(const bf16x8*)(Bs + r * 64 + (((kk * 4 + l4) ^ (r & 7)) * 8));
            }
        }
        __builtin_amdgcn_s_setprio(1);
#pragma unroll
        for (int kk = 0; kk < 2; kk++)
#pragma unroll
            for (int i = 0; i < 4; i++)
#pragma unroll
                for (int j = 0; j < 2; j++)
                    acc[i][j] = __builtin_amdgcn_mfma_f32_16x16x32_bf16(af[kk][i], bfv[kk][j], acc[i][j], 0, 0, 0);
        __builtin_amdgcn_s_setprio(0);
        __syncthreads();
    }

#pragma unroll
    for (int i = 0; i < 4; i++)
#pragma unroll
        for (int j = 0; j < 2; j++)
#pragma unroll
            for (int r = 0; r < 4; r++) {
                int row = mbase + wr * 64 + i * 16 + l4 * 4 + r;
                int col = nbase + wc * 32 + j * 16 + l15;
                C[(size_t)row * N + col] = acc[i][j][r] + bias[col];
            }
}

// ---------------- attention ----------------
// 512-thread blocks: 8 waves share one K/V tile (halves per-CU staging+barriers).
// T15 skew with lagged cooperative V staging; one barrier per tile.
__device__ __forceinline__ int invrow(int R) {  // logical LDS row -> klocal
    return 32 * (R >> 5) + 8 * ((R >> 2) & 3) + 4 * ((R >> 4) & 1) + (R & 3);
}

__global__ __launch_bounds__(512, 4)
void attn_kernel(const u16* __restrict__ Qb, const u16* __restrict__ Kb,
                 const u16* __restrict__ VT, u16* __restrict__ Ob)
{
    const int qt = blockIdx.x;   // 0..15 (128 q-rows each)
    const int bh = blockIdx.y;   // 0..31
    const int b = bh >> 4, h = bh & 15;
    __shared__ __align__(16) u16 Ks[2][4096];
    __shared__ __align__(16) u16 Vs[2][4096];
    const int tid = threadIdx.x, wv = tid >> 6, lane = tid & 63;  // wv 0..7
    const int l15 = lane & 15, l4 = lane >> 4;

    const int r8 = lane >> 3;
    const int cp = lane & 7;
    const int cl = cp ^ r8;
    const int RK = wv * 8 + r8;                 // each wave stages one 8-row segment
    const u16* ksrc = Kb + (size_t)(b * 2048 + invrow(RK)) * 1024 + h * 64 + cl * 8;
    const u16* vsrc = VT + (size_t)(h * 64 + RK) * 4096 + b * 2048 + cl * 8;

    const u16* qrow = Qb + (size_t)(b * 2048 + qt * 128 + wv * 16 + l15) * 1024 + h * 64;
    bf16x8 qf0 = *(const bf16x8*)(qrow + l4 * 8);
    bf16x8 qf1 = *(const bf16x8*)(qrow + 32 + l4 * 8);

    const int swz = l15 & 7;
    const int q0o = (l4 ^ swz) * 8;
    const int q1o = ((4 + l4) ^ swz) * 8;

    f32x4 accO[4];
    float denom = 0.f;
#pragma unroll
    for (int i = 0; i < 4; i++) accO[i] = (f32x4){0.f, 0.f, 0.f, 0.f};

    auto stageK = [&](int bs, int kt) {
        gload_lds16(ksrc + (size_t)kt * 65536, (void*)&Ks[bs][wv * 512]);
    };
    auto stageV = [&](int bs, int kt) {
        gload_lds16(vsrc + kt * 64, (void*)&Vs[bs][wv * 512]);
    };

    stageK(0, 0);
    __syncthreads();

    f32x4 sA[4], sB[4];

    auto finish_tile = [&](f32x4 (&sold)[4], int vbuf) {
        float p[4][4];
        float rs = 0.f;
#pragma unroll
        for (int j = 0; j < 4; j++)
#pragma unroll
            for (int r = 0; r < 4; r++) {
                p[j][r] = fexp2(sold[j][r]);
                rs += p[j][r];
            }
        rs += __shfl_xor(rs, 16);
        rs += __shfl_xor(rs, 32);
        denom += rs;
        union { uint32_t u[4]; bf16x8 v; } B0u, B1u;
        B0u.u[0] = cvt_pk_bf16(p[0][0], p[0][1]);
        B0u.u[1] = cvt_pk_bf16(p[0][2], p[0][3]);
        B0u.u[2] = cvt_pk_bf16(p[1][0], p[1][1]);
        B0u.u[3] = cvt_pk_bf16(p[1][2], p[1][3]);
        B1u.u[0] = cvt_pk_bf16(p[2][0], p[2][1]);
        B1u.u[1] = cvt_pk_bf16(p[2][2], p[2][3]);
        B1u.u[2] = cvt_pk_bf16(p[3][0], p[3][1]);
        B1u.u[3] = cvt_pk_bf16(p[3][2], p[3][3]);
        __builtin_amdgcn_s_setprio(1);
#pragma unroll
        for (int i = 0; i < 4; i++) {
            const u16* vp = &Vs[vbuf][(i * 16 + l15) * 64];
            bf16x8 v0 = *(const bf16x8*)(vp + q0o);
            bf16x8 v1 = *(const bf16x8*)(vp + q1o);
            accO[i] = __builtin_amdgcn_mfma_f32_16x16x32_bf16(v0, B0u.v, accO[i], 0, 0, 0);
            accO[i] = __builtin_amdgcn_mfma_f32_16x16x32_bf16(v1, B1u.v, accO[i], 0, 0, 0);
        }
        __builtin_amdgcn_s_setprio(0);
    };

    auto body = [&](int kt, f32x4 (&snew)[4], f32x4 (&sold)[4]) {
        const int kb = kt & 1;
#pragma unroll
        for (int j = 0; j < 4; j++) snew[j] = (f32x4){0.f, 0.f, 0.f, 0.f};
        __builtin_amdgcn_s_setprio(1);
#pragma unroll
        for (int j = 0; j < 4; j++) {
            const u16* rp = &Ks[kb][(j * 16 + l15) * 64];
            bf16x8 a0 = *(const bf16x8*)(rp + q0o);
            bf16x8 a1 = *(const bf16x8*)(rp + q1o);
            snew[j] = __builtin_amdgcn_mfma_f32_16x16x32_bf16(a0, qf0, snew[j], 0, 0, 0);
            snew[j] = __builtin_amdgcn_mfma_f32_16x16x32_bf16(a1, qf1, snew[j], 0, 0, 0);
        }
        __builtin_amdgcn_s_setprio(0);
        if (kt < 31) stageK(kb ^ 1, kt + 1);
        stageV(kb ^ 1, kt);
        if (kt > 0) finish_tile(sold, kb);
        __syncthreads();
    };

    for (int kt2 = 0; kt2 < 32; kt2 += 2) {
        body(kt2, sA, sB);
        body(kt2 + 1, sB, sA);
    }
    // epilogue: tile 31 (s in sB, V[31] staged into buffer 0)
    finish_tile(sB, 0);

    float rd = 1.0f / denom;
    u16* orow = Ob + (size_t)(b * 2048 + qt * 128 + wv * 16 + l15) * 1024 + h * 64;
#pragma unroll
    for (int i = 0; i < 4; i++) {
        uint2 st;
        st.x = cvt_pk_bf16(accO[i][0] * rd, accO[i][1] * rd);
        st.y = cvt_pk_bf16(accO[i][2] * rd, accO[i][3] * rd);
        *(uint2*)(orow + i * 16 + l4 * 4) = st;
    }
}

extern "C" void kernel_launch(void* const* d_in, const int* in_sizes, int n_in,
                              void* d_out, int out_size, void* d_ws, size_t ws_size,
                              hipStream_t stream) {
    const float* x   = (const float*)d_in[0];
    const float* ctx = (const float*)d_in[1];
    const float* Wq  = (const float*)d_in[2];
    const float* bq  = (const float*)d_in[3];
    const float* Wk  = (const float*)d_in[4];
    const float* bk  = (const float*)d_in[5];
    const float* Wv  = (const float*)d_in[6];
    const float* bv  = (const float*)d_in[7];
    const float* Wo  = (const float*)d_in[8];
    const float* bo  = (const float*)d_in[9];
    float* out = (float*)d_out;

    char* ws = (char*)d_ws;
    size_t off = 0;
    auto alloc = [&](size_t bytes) { void* p = ws + off; off += (bytes + 255) & ~255ULL; return p; };
    u16* x_bf  = (u16*)alloc(4096ULL * 1024 * 2);
    u16* c_bf  = (u16*)alloc(4096ULL * 1152 * 2);
    u16* wq_bf = (u16*)alloc(1024ULL * 1024 * 2);
    u16* wk_bf = (u16*)alloc(1024ULL * 1152 * 2);
    u16* wv_bf = (u16*)alloc(1024ULL * 1152 * 2);
    u16* wo_bf = (u16*)alloc(1024ULL * 1024 * 2);
    float2* cs = (float2*)alloc(2048ULL * 32 * 8);
    u16* q_bf  = (u16*)alloc(4096ULL * 1024 * 2);
    u16* k_bf  = (u16*)alloc(4096ULL * 1024 * 2);
    u16* vT    = (u16*)alloc(1024ULL * 4096 * 2);
    u16* a_bf  = (u16*)alloc(4096ULL * 1024 * 2);

    prep_kernel<<<13312, 256, 0, stream>>>(x, ctx, Wq, Wk, Wv, Wo,
                                           x_bf, c_bf, wq_bf, wk_bf, wv_bf, wo_bf, cs);
    qkv_gemm<<<768, 256, 0, stream>>>(x_bf, c_bf, wq_bf, wk_bf, wv_bf,
                                      bq, bk, bv, q_bf, k_bf, vT, cs);
    attn_kernel<<<dim3(16, 32), 512, 0, stream>>>(q_bf, k_bf, vT, a_bf);
    gemm_out<<<dim3(16, 32), 256, 0, stream>>>(a_bf, wo_bf, bo, out, 4096, 1024, 1024);
}